// Round 1
// baseline (2369.698 us; speedup 1.0000x reference)
//
#include <hip/hip_runtime.h>
#include <math.h>

#define NHEADS 16
#define HD 64
#define MMEM 16384
#define NQ 1024   // B*S per head
#define SEQ 512
#define EPS 1e-8f

// ---------------------------------------------------------------------------
// Kernel 1: reciprocal L2 norm of each key-memory row: knr[h*M+m] = 1/max(||k||,eps)
// 16 lanes cooperate per row (coalesced float4 reads), shfl-xor reduce.
// ---------------------------------------------------------------------------
__global__ void knorm_kernel(const float* __restrict__ kmem,
                             float* __restrict__ knr) {
    int gid = blockIdx.x * 256 + threadIdx.x;
    int mem = gid >> 4;   // 0 .. NHEADS*MMEM-1
    int d4  = gid & 15;
    float4 kv = reinterpret_cast<const float4*>(kmem)[(size_t)mem * 16 + d4];
    float ss = kv.x * kv.x + kv.y * kv.y + kv.z * kv.z + kv.w * kv.w;
    ss += __shfl_xor(ss, 1);
    ss += __shfl_xor(ss, 2);
    ss += __shfl_xor(ss, 4);
    ss += __shfl_xor(ss, 8);
    if (d4 == 0) knr[mem] = 1.0f / fmaxf(sqrtf(ss), EPS);
}

// ---------------------------------------------------------------------------
// Kernel 2: similarity scan + per-lane running top-8.
// Wave = 64 queries (one per lane, query held in 64 VGPRs, pre-scaled by
// 1/(max(||q||,eps)*8)). The wave iterates a uniform chunk of memories; the
// key-row address is wave-uniform so loads can go scalar/broadcast.
// ---------------------------------------------------------------------------
__global__ void scan_kernel(const float* __restrict__ query,
                            const float* __restrict__ kmem,
                            const float* __restrict__ knr,
                            float* __restrict__ pscore,
                            int* __restrict__ pidx,
                            int P, int CH) {
    const int lane = threadIdx.x & 63;
    const int wid  = threadIdx.x >> 6;
    const int pg_per = P >> 2;           // part-groups per (h,qb)
    int bid = blockIdx.x;
    const int pg = bid % pg_per; bid /= pg_per;
    const int qb = bid & 15;     bid >>= 4;
    const int h  = bid;
    const int p  = pg * 4 + wid;
    const int n  = qb * 64 + lane;       // query index within head
    const int b  = n >> 9;
    const int s  = n & 511;

    // load query, compute norm, fold 1/(max(norm,eps)*sqrt(64)) into q
    const float4* qp = reinterpret_cast<const float4*>(
        query + (((size_t)b * NHEADS + h) * SEQ + s) * HD);
    float q[HD];
    float ss = 0.0f;
#pragma unroll
    for (int i = 0; i < 16; ++i) {
        float4 v = qp[i];
        q[4*i+0] = v.x; q[4*i+1] = v.y; q[4*i+2] = v.z; q[4*i+3] = v.w;
        ss += v.x * v.x + v.y * v.y + v.z * v.z + v.w * v.w;
    }
    const float rq = 1.0f / (fmaxf(sqrtf(ss), EPS) * 8.0f);
#pragma unroll
    for (int i = 0; i < HD; ++i) q[i] *= rq;

    float tv[8]; int ti[8];
#pragma unroll
    for (int j = 0; j < 8; ++j) { tv[j] = -INFINITY; ti[j] = 0; }

    const int m0 = p * CH;
    const float4* kp = reinterpret_cast<const float4*>(
        kmem + ((size_t)h * MMEM + m0) * HD);
    const float* knrp = knr + h * MMEM + m0;

    for (int mm = 0; mm < CH; ++mm) {
        float d0 = 0.f, d1 = 0.f, d2 = 0.f, d3 = 0.f;
#pragma unroll
        for (int i = 0; i < 16; ++i) {
            float4 kv = kp[(size_t)mm * 16 + i];   // wave-uniform
            d0 = fmaf(q[4*i+0], kv.x, d0);
            d1 = fmaf(q[4*i+1], kv.y, d1);
            d2 = fmaf(q[4*i+2], kv.z, d2);
            d3 = fmaf(q[4*i+3], kv.w, d3);
        }
        const float sim = ((d0 + d1) + (d2 + d3)) * knrp[mm];
        if (sim > tv[7]) {                 // strict > keeps lower index on ties
            tv[7] = sim; ti[7] = m0 + mm;
#pragma unroll
            for (int j = 7; j > 0; --j) {
                if (tv[j] > tv[j-1]) {
                    float tf = tv[j]; tv[j] = tv[j-1]; tv[j-1] = tf;
                    int   tu = ti[j]; ti[j] = ti[j-1]; ti[j-1] = tu;
                }
            }
        }
    }

    const size_t base = (((size_t)h * NQ + n) * P + p) * 8;
#pragma unroll
    for (int j = 0; j < 8; ++j) { pscore[base+j] = tv[j]; pidx[base+j] = ti[j]; }
}

// ---------------------------------------------------------------------------
// Kernel 3: merge P partial top-8 lists per query (ascending-partition order
// preserves lower-index-first ties), gather top-8 value rows, weighted sum,
// sigmoid-gate blend with `outputs`.
// ---------------------------------------------------------------------------
__global__ void merge_kernel(const float* __restrict__ pscore,
                             const int* __restrict__ pidx,
                             const float* __restrict__ vmem,
                             const float* __restrict__ outputs,
                             const float* __restrict__ gate,
                             float* __restrict__ out, int P) {
    const int t = blockIdx.x * 256 + threadIdx.x;   // 0 .. NHEADS*NQ-1
    const int h = t >> 10;
    const int n = t & 1023;
    const int b = n >> 9;
    const int s = n & 511;

    float tv[8]; int ti[8];
    const size_t base = ((size_t)h * NQ + n) * P * 8;
#pragma unroll
    for (int j = 0; j < 8; ++j) { tv[j] = pscore[base+j]; ti[j] = pidx[base+j]; }
    const int total = P * 8;
    for (int c = 8; c < total; ++c) {
        const float v = pscore[base + c];
        if (v > tv[7]) {
            tv[7] = v; ti[7] = pidx[base + c];
#pragma unroll
            for (int j = 7; j > 0; --j) {
                if (tv[j] > tv[j-1]) {
                    float tf = tv[j]; tv[j] = tv[j-1]; tv[j-1] = tf;
                    int   tu = ti[j]; ti[j] = ti[j-1]; ti[j-1] = tu;
                }
            }
        }
    }

    float4 acc[16];
#pragma unroll
    for (int i = 0; i < 16; ++i) acc[i] = make_float4(0.f, 0.f, 0.f, 0.f);
#pragma unroll
    for (int j = 0; j < 8; ++j) {
        const float4* vp = reinterpret_cast<const float4*>(
            vmem + ((size_t)h * MMEM + ti[j]) * HD);
        const float sc = tv[j];
#pragma unroll
        for (int i = 0; i < 16; ++i) {
            float4 v = vp[i];
            acc[i].x = fmaf(sc, v.x, acc[i].x);
            acc[i].y = fmaf(sc, v.y, acc[i].y);
            acc[i].z = fmaf(sc, v.z, acc[i].z);
            acc[i].w = fmaf(sc, v.w, acc[i].w);
        }
    }

    const float g  = 1.0f / (1.0f + expf(-gate[h]));
    const float og = 1.0f - g;
    const size_t off = (((size_t)b * NHEADS + h) * SEQ + s) * HD;
    const float4* op = reinterpret_cast<const float4*>(outputs + off);
    float4* dst = reinterpret_cast<float4*>(out + off);
#pragma unroll
    for (int i = 0; i < 16; ++i) {
        float4 o = op[i];
        float4 r;
        r.x = g * acc[i].x + og * o.x;
        r.y = g * acc[i].y + og * o.y;
        r.z = g * acc[i].z + og * o.z;
        r.w = g * acc[i].w + og * o.w;
        dst[i] = r;
    }
}

// ---------------------------------------------------------------------------
extern "C" void kernel_launch(void* const* d_in, const int* in_sizes, int n_in,
                              void* d_out, int out_size, void* d_ws, size_t ws_size,
                              hipStream_t stream) {
    // setup_inputs order: inputs, query, key, value, outputs, gate,
    //                     key_memories, value_memories
    const float* query   = (const float*)d_in[1];
    const float* outputs = (const float*)d_in[4];
    const float* gate    = (const float*)d_in[5];
    const float* kmem    = (const float*)d_in[6];
    const float* vmem    = (const float*)d_in[7];
    float* out = (float*)d_out;

    // workspace: knr (1 MB) + pscore/pidx partials (P MB total, 64B/query/part)
    int P = 16;
    while (P > 4 &&
           (size_t)NHEADS * MMEM * 4 + (size_t)NHEADS * NQ * (size_t)P * 64 > ws_size)
        P >>= 1;
    const int CH = MMEM / P;

    float* knr    = (float*)d_ws;
    float* pscore = knr + (size_t)NHEADS * MMEM;
    int*   pidx   = (int*)(pscore + (size_t)NHEADS * NQ * (size_t)P * 8);

    knorm_kernel<<<(NHEADS * MMEM * 16) / 256, 256, 0, stream>>>(kmem, knr);
    scan_kernel<<<NHEADS * 16 * (P / 4), 256, 0, stream>>>(
        query, kmem, knr, pscore, pidx, P, CH);
    merge_kernel<<<(NHEADS * NQ) / 256, 256, 0, stream>>>(
        pscore, pidx, vmem, outputs, gate, out, P);
}

// Round 2
// 1336.259 us; speedup vs baseline: 1.7734x; 1.7734x over previous
//
#include <hip/hip_runtime.h>
#include <math.h>

#define NHEADS 16
#define HD 64
#define MMEM 16384
#define NQ 1024   // B*S per head
#define SEQ 512
#define EPS 1e-8f

// ---------------------------------------------------------------------------
// Kernel 1: reciprocal L2 norm of each key-memory row: knr[h*M+m] = 1/max(||k||,eps)
// 16 lanes cooperate per row (coalesced float4 reads), shfl-xor reduce.
// ---------------------------------------------------------------------------
__global__ void knorm_kernel(const float* __restrict__ kmem,
                             float* __restrict__ knr) {
    int gid = blockIdx.x * 256 + threadIdx.x;
    int mem = gid >> 4;   // 0 .. NHEADS*MMEM-1
    int d4  = gid & 15;
    float4 kv = reinterpret_cast<const float4*>(kmem)[(size_t)mem * 16 + d4];
    float ss = kv.x * kv.x + kv.y * kv.y + kv.z * kv.z + kv.w * kv.w;
    ss += __shfl_xor(ss, 1);
    ss += __shfl_xor(ss, 2);
    ss += __shfl_xor(ss, 4);
    ss += __shfl_xor(ss, 8);
    if (d4 == 0) knr[mem] = 1.0f / fmaxf(sqrtf(ss), EPS);
}

// ---------------------------------------------------------------------------
// Kernel 2: similarity scan + per-lane running top-8.
// One wave per block (__launch_bounds__(64,4) -> 128-VGPR cap, q[] stays in
// registers, 4 waves/SIMD). Wave = 64 queries (one per lane, query held in
// 64 VGPRs, pre-scaled by 1/(max(||q||,eps)*8)). The wave iterates a uniform
// chunk of memories; k-row addresses are wave-uniform (broadcast from L2).
// ---------------------------------------------------------------------------
__global__ __launch_bounds__(64, 4)
void scan_kernel(const float* __restrict__ query,
                 const float* __restrict__ kmem,
                 const float* __restrict__ knr,
                 float* __restrict__ pscore,
                 int* __restrict__ pidx,
                 int P, int CH) {
    const int lane = threadIdx.x & 63;
    int bid = blockIdx.x;
    const int p  = bid % P;  bid /= P;
    const int qb = bid & 15; bid >>= 4;
    const int h  = bid;
    const int n  = qb * 64 + lane;       // query index within head
    const int b  = n >> 9;
    const int s  = n & 511;

    // load query, compute norm, fold 1/(max(norm,eps)*sqrt(64)) into q
    const float4* qp = reinterpret_cast<const float4*>(
        query + (((size_t)b * NHEADS + h) * SEQ + s) * HD);
    float q[HD];
    float ss = 0.0f;
#pragma unroll
    for (int i = 0; i < 16; ++i) {
        float4 v = qp[i];
        q[4*i+0] = v.x; q[4*i+1] = v.y; q[4*i+2] = v.z; q[4*i+3] = v.w;
        ss += v.x * v.x + v.y * v.y + v.z * v.z + v.w * v.w;
    }
    const float rq = 1.0f / (fmaxf(sqrtf(ss), EPS) * 8.0f);
#pragma unroll
    for (int i = 0; i < HD; ++i) q[i] *= rq;

    float tv[8]; int ti[8];
#pragma unroll
    for (int j = 0; j < 8; ++j) { tv[j] = -INFINITY; ti[j] = 0; }

    const int m0 = p * CH;
    const float4* kp = reinterpret_cast<const float4*>(
        kmem + ((size_t)h * MMEM + m0) * HD);
    const float* knrp = knr + h * MMEM + m0;

    for (int mm = 0; mm < CH; ++mm) {
        float d0 = 0.f, d1 = 0.f, d2 = 0.f, d3 = 0.f;
#pragma unroll
        for (int i = 0; i < 16; ++i) {
            float4 kv = kp[(size_t)mm * 16 + i];   // wave-uniform -> broadcast
            d0 = fmaf(q[4*i+0], kv.x, d0);
            d1 = fmaf(q[4*i+1], kv.y, d1);
            d2 = fmaf(q[4*i+2], kv.z, d2);
            d3 = fmaf(q[4*i+3], kv.w, d3);
        }
        const float sim = ((d0 + d1) + (d2 + d3)) * knrp[mm];
        if (sim > tv[7]) {                 // strict > keeps lower index on ties
            tv[7] = sim; ti[7] = m0 + mm;
#pragma unroll
            for (int j = 7; j > 0; --j) {
                if (tv[j] > tv[j-1]) {
                    float tf = tv[j]; tv[j] = tv[j-1]; tv[j-1] = tf;
                    int   tu = ti[j]; ti[j] = ti[j-1]; ti[j-1] = tu;
                }
            }
        }
    }

    const size_t base = (((size_t)h * NQ + n) * P + p) * 8;
#pragma unroll
    for (int j = 0; j < 8; ++j) { pscore[base+j] = tv[j]; pidx[base+j] = ti[j]; }
}

// ---------------------------------------------------------------------------
// Kernel 3: merge P partial top-8 lists per query (ascending-partition order
// preserves lower-index-first ties), gather top-8 value rows, weighted sum,
// sigmoid-gate blend with `outputs`.
// ---------------------------------------------------------------------------
__global__ void merge_kernel(const float* __restrict__ pscore,
                             const int* __restrict__ pidx,
                             const float* __restrict__ vmem,
                             const float* __restrict__ outputs,
                             const float* __restrict__ gate,
                             float* __restrict__ out, int P) {
    const int t = blockIdx.x * 256 + threadIdx.x;   // 0 .. NHEADS*NQ-1
    const int h = t >> 10;
    const int n = t & 1023;
    const int b = n >> 9;
    const int s = n & 511;

    float tv[8]; int ti[8];
    const size_t base = ((size_t)h * NQ + n) * P * 8;
#pragma unroll
    for (int j = 0; j < 8; ++j) { tv[j] = pscore[base+j]; ti[j] = pidx[base+j]; }
    const int total = P * 8;
    for (int c = 8; c < total; ++c) {
        const float v = pscore[base + c];
        if (v > tv[7]) {
            tv[7] = v; ti[7] = pidx[base + c];
#pragma unroll
            for (int j = 7; j > 0; --j) {
                if (tv[j] > tv[j-1]) {
                    float tf = tv[j]; tv[j] = tv[j-1]; tv[j-1] = tf;
                    int   tu = ti[j]; ti[j] = ti[j-1]; ti[j-1] = tu;
                }
            }
        }
    }

    float4 acc[16];
#pragma unroll
    for (int i = 0; i < 16; ++i) acc[i] = make_float4(0.f, 0.f, 0.f, 0.f);
#pragma unroll
    for (int j = 0; j < 8; ++j) {
        const float4* vp = reinterpret_cast<const float4*>(
            vmem + ((size_t)h * MMEM + ti[j]) * HD);
        const float sc = tv[j];
#pragma unroll
        for (int i = 0; i < 16; ++i) {
            float4 v = vp[i];
            acc[i].x = fmaf(sc, v.x, acc[i].x);
            acc[i].y = fmaf(sc, v.y, acc[i].y);
            acc[i].z = fmaf(sc, v.z, acc[i].z);
            acc[i].w = fmaf(sc, v.w, acc[i].w);
        }
    }

    const float g  = 1.0f / (1.0f + expf(-gate[h]));
    const float og = 1.0f - g;
    const size_t off = (((size_t)b * NHEADS + h) * SEQ + s) * HD;
    const float4* op = reinterpret_cast<const float4*>(outputs + off);
    float4* dst = reinterpret_cast<float4*>(out + off);
#pragma unroll
    for (int i = 0; i < 16; ++i) {
        float4 o = op[i];
        float4 r;
        r.x = g * acc[i].x + og * o.x;
        r.y = g * acc[i].y + og * o.y;
        r.z = g * acc[i].z + og * o.z;
        r.w = g * acc[i].w + og * o.w;
        dst[i] = r;
    }
}

// ---------------------------------------------------------------------------
extern "C" void kernel_launch(void* const* d_in, const int* in_sizes, int n_in,
                              void* d_out, int out_size, void* d_ws, size_t ws_size,
                              hipStream_t stream) {
    // setup_inputs order: inputs, query, key, value, outputs, gate,
    //                     key_memories, value_memories
    const float* query   = (const float*)d_in[1];
    const float* outputs = (const float*)d_in[4];
    const float* gate    = (const float*)d_in[5];
    const float* kmem    = (const float*)d_in[6];
    const float* vmem    = (const float*)d_in[7];
    float* out = (float*)d_out;

    // workspace: knr (1 MB) + pscore/pidx partials (P MB total, 64B/query/part)
    int P = 16;
    while (P > 4 &&
           (size_t)NHEADS * MMEM * 4 + (size_t)NHEADS * NQ * (size_t)P * 64 > ws_size)
        P >>= 1;
    const int CH = MMEM / P;

    float* knr    = (float*)d_ws;
    float* pscore = knr + (size_t)NHEADS * MMEM;
    int*   pidx   = (int*)(pscore + (size_t)NHEADS * NQ * (size_t)P * 8);

    knorm_kernel<<<(NHEADS * MMEM * 16) / 256, 256, 0, stream>>>(kmem, knr);
    scan_kernel<<<NHEADS * 16 * P, 64, 0, stream>>>(
        query, kmem, knr, pscore, pidx, P, CH);
    merge_kernel<<<(NHEADS * NQ) / 256, 256, 0, stream>>>(
        pscore, pidx, vmem, outputs, gate, out, P);
}